// Round 2
// baseline (532.888 us; speedup 1.0000x reference)
//
#include <hip/hip_runtime.h>
#include <math.h>

#define NB 32768          // B
#define NSEG 65536        // 2*B
#define NRF 11            // read features
#define NIF 9             // info features

// ---------------------------------------------------------------------------
// K1: per-read phi MLP (11 -> 64 relu -> 64 sigmoid) + segment mean.
// One wave per segment (8 segments per wave). lane = output feature.
// Weights held per-lane in VGPRs; read features via wave-uniform loads;
// hidden layer broadcast through per-wave LDS (float4 reads).
// ---------------------------------------------------------------------------
__global__ __launch_bounds__(256) void k1_phi_segmean(
    const float* __restrict__ reads,
    const int* __restrict__ endi,
    const float* __restrict__ w0, const float* __restrict__ b0,
    const float* __restrict__ w1, const float* __restrict__ b1,
    float* __restrict__ means)
{
    __shared__ float hbuf[4][64];
    const int lane = threadIdx.x & 63;
    const int wid  = threadIdx.x >> 6;
    const int wg   = __builtin_amdgcn_readfirstlane((int)(blockIdx.x * 4 + wid));

    float w0c[NRF];
#pragma unroll
    for (int k = 0; k < NRF; ++k) w0c[k] = w0[k * 64 + lane];
    float w1c[64];
#pragma unroll
    for (int i = 0; i < 64; ++i) w1c[i] = w1[i * 64 + lane];
    const float b0l = b0[lane];
    const float b1l = b1[lane];

    for (int i = 0; i < 8; ++i) {
        const int s = wg * 8 + i;
        const int r1 = endi[s];
        const int r0 = (s == 0) ? 0 : endi[s - 1];
        float acc = 0.f;
        for (int r = r0; r < r1; ++r) {
            const float* __restrict__ x = reads + (size_t)r * NRF;  // wave-uniform addr
            float h = b0l;
#pragma unroll
            for (int k = 0; k < NRF; ++k) h = fmaf(x[k], w0c[k], h);
            h = fmaxf(h, 0.f);
            hbuf[wid][lane] = h;
            float o = b1l;
            const float4* h4 = (const float4*)(&hbuf[wid][0]);
#pragma unroll
            for (int q = 0; q < 16; ++q) {
                float4 hv = h4[q];
                o = fmaf(hv.x, w1c[4 * q + 0], o);
                o = fmaf(hv.y, w1c[4 * q + 1], o);
                o = fmaf(hv.z, w1c[4 * q + 2], o);
                o = fmaf(hv.w, w1c[4 * q + 3], o);
            }
            acc += 1.f / (1.f + __expf(-o));
        }
        means[(size_t)s * 64 + lane] = acc / (float)(r1 - r0);
    }
}

// ---------------------------------------------------------------------------
// K2: omega MLP on info (9 -> 64 relu -> 64 sigmoid). Wave per 8 rows.
// ---------------------------------------------------------------------------
__global__ __launch_bounds__(256) void k2_omega(
    const float* __restrict__ info,
    const float* __restrict__ w0, const float* __restrict__ b0,
    const float* __restrict__ w1, const float* __restrict__ b1,
    float* __restrict__ om)
{
    __shared__ float hbuf[4][64];
    const int lane = threadIdx.x & 63;
    const int wid  = threadIdx.x >> 6;
    const int wg   = __builtin_amdgcn_readfirstlane((int)(blockIdx.x * 4 + wid));

    float w0c[NIF];
#pragma unroll
    for (int k = 0; k < NIF; ++k) w0c[k] = w0[k * 64 + lane];
    float w1c[64];
#pragma unroll
    for (int i = 0; i < 64; ++i) w1c[i] = w1[i * 64 + lane];
    const float b0l = b0[lane];
    const float b1l = b1[lane];

    for (int i = 0; i < 8; ++i) {
        const int b = wg * 8 + i;
        const float* __restrict__ x = info + (size_t)b * NIF;  // wave-uniform
        float h = b0l;
#pragma unroll
        for (int k = 0; k < NIF; ++k) h = fmaf(x[k], w0c[k], h);
        h = fmaxf(h, 0.f);
        hbuf[wid][lane] = h;
        float o = b1l;
        const float4* h4 = (const float4*)(&hbuf[wid][0]);
#pragma unroll
        for (int q = 0; q < 16; ++q) {
            float4 hv = h4[q];
            o = fmaf(hv.x, w1c[4 * q + 0], o);
            o = fmaf(hv.y, w1c[4 * q + 1], o);
            o = fmaf(hv.z, w1c[4 * q + 2], o);
            o = fmaf(hv.w, w1c[4 * q + 3], o);
        }
        om[(size_t)b * 64 + lane] = 1.f / (1.f + __expf(-o));
    }
}

// ---------------------------------------------------------------------------
// K3: rho MLP (192 -> 128 relu -> 64 relu -> 1), cal MLP (2->5->5->1),
// calibrated tanh clamp. One wave per 64 batch elements (lane = element).
// x staged through LDS 64x64 tile transpose (pad 65 -> conflict-free);
// all weights wave-uniform -> scalar loads.
// ---------------------------------------------------------------------------
__global__ __launch_bounds__(64) void k3_rho_cal(
    const float* __restrict__ means, const float* __restrict__ om,
    const int* __restrict__ endi,
    const float* __restrict__ rw0, const float* __restrict__ rb0,
    const float* __restrict__ rw1, const float* __restrict__ rb1,
    const float* __restrict__ rw2, const float* __restrict__ rb2,
    const float* __restrict__ cw0, const float* __restrict__ cb0,
    const float* __restrict__ cw1, const float* __restrict__ cb1,
    const float* __restrict__ cw2, const float* __restrict__ cb2,
    const float* __restrict__ max_logit,
    float* __restrict__ out)
{
    __shared__ float xl[64 * 65];
    const int lane = threadIdx.x;
    const int b0i  = blockIdx.x * 64;
    const int b    = b0i + lane;

    float acc[128];
#pragma unroll
    for (int j = 0; j < 128; ++j) acc[j] = rb0[j];

    // c = 0: ref_means rows [0,B); c = 1: alt_means rows [B,2B); c = 2: omega
    for (int c = 0; c < 3; ++c) {
        const float* __restrict__ src =
            (c == 0) ? means + (size_t)b0i * 64 :
            (c == 1) ? means + (size_t)(NB + b0i) * 64 :
                       om    + (size_t)b0i * 64;
        // stage 64x64 tile (coalesced loads), transposed consumption below
#pragma unroll 8
        for (int r = 0; r < 64; ++r) xl[r * 65 + lane] = src[(size_t)r * 64 + lane];
        // same-wave LDS ops are ordered; no barrier needed (single wave)
        for (int k = 0; k < 64; ++k) {
            const float xk = xl[lane * 65 + k];
            const float* __restrict__ w = rw0 + (size_t)(c * 64 + k) * 128;  // uniform
#pragma unroll
            for (int j = 0; j < 128; ++j) acc[j] = fmaf(xk, w[j], acc[j]);
        }
    }

    float h2[64];
#pragma unroll
    for (int j = 0; j < 64; ++j) h2[j] = rb1[j];
#pragma unroll
    for (int i = 0; i < 128; ++i) {
        const float a = fmaxf(acc[i], 0.f);
#pragma unroll
        for (int j = 0; j < 64; ++j) h2[j] = fmaf(a, rw1[i * 64 + j], h2[j]);
    }

    float logit = rb2[0];
#pragma unroll
    for (int j = 0; j < 64; ++j) logit = fmaf(fmaxf(h2[j], 0.f), rw2[j], logit);

    // calibration: x0 = sqrt(eff_alt), x1 = sqrt(eff_ref); eff = count (weights==1)
    const int er1 = endi[b];
    const int er0 = (b == 0) ? 0 : endi[b - 1];
    const int ea1 = endi[NB + b];
    const int ea0 = endi[NB + b - 1];
    const float x0 = sqrtf((float)(ea1 - ea0));
    const float x1 = sqrtf((float)(er1 - er0));

    float t5[5];
#pragma unroll
    for (int m = 0; m < 5; ++m)
        t5[m] = fmaxf(cb0[m] + x0 * cw0[m] + x1 * cw0[5 + m], 0.f);
    float t5b[5];
#pragma unroll
    for (int m = 0; m < 5; ++m) {
        float v = cb1[m];
#pragma unroll
        for (int i = 0; i < 5; ++i) v = fmaf(t5[i], cw1[i * 5 + m], v);
        t5b[m] = fmaxf(v, 0.f);
    }
    float temp = cb2[0];
#pragma unroll
    for (int m = 0; m < 5; ++m) temp = fmaf(t5b[m], cw2[m], temp);

    const float ml = max_logit[0];
    out[b] = ml * tanhf((logit * temp) / ml);
}

// ---------------------------------------------------------------------------
extern "C" void kernel_launch(void* const* d_in, const int* in_sizes, int n_in,
                              void* d_out, int out_size, void* d_ws, size_t ws_size,
                              hipStream_t stream)
{
    const float* reads  = (const float*)d_in[0];
    const float* info   = (const float*)d_in[1];
    const int*   endi   = (const int*)d_in[2];       // harness converts ints to int32
    const float* phi_w0 = (const float*)d_in[3];
    const float* phi_b0 = (const float*)d_in[4];
    const float* phi_w1 = (const float*)d_in[5];
    const float* phi_b1 = (const float*)d_in[6];
    const float* om_w0  = (const float*)d_in[7];
    const float* om_b0  = (const float*)d_in[8];
    const float* om_w1  = (const float*)d_in[9];
    const float* om_b1  = (const float*)d_in[10];
    const float* rw0    = (const float*)d_in[11];
    const float* rb0    = (const float*)d_in[12];
    const float* rw1    = (const float*)d_in[13];
    const float* rb1    = (const float*)d_in[14];
    const float* rw2    = (const float*)d_in[15];
    const float* rb2    = (const float*)d_in[16];
    const float* cw0    = (const float*)d_in[17];
    const float* cb0    = (const float*)d_in[18];
    const float* cw1    = (const float*)d_in[19];
    const float* cb1    = (const float*)d_in[20];
    const float* cw2    = (const float*)d_in[21];
    const float* cb2    = (const float*)d_in[22];
    const float* mlog   = (const float*)d_in[23];

    float* means = (float*)d_ws;                       // 65536*64 fp32 = 16.78 MB
    float* om    = means + (size_t)NSEG * 64;          // 32768*64 fp32 =  8.39 MB
    float* out   = (float*)d_out;

    // K1: 65536 segments, 8 per wave, 4 waves/block -> 2048 blocks
    hipLaunchKernelGGL(k1_phi_segmean, dim3(2048), dim3(256), 0, stream,
                       reads, endi, phi_w0, phi_b0, phi_w1, phi_b1, means);
    // K2: 32768 rows, 8 per wave, 4 waves/block -> 1024 blocks
    hipLaunchKernelGGL(k2_omega, dim3(1024), dim3(256), 0, stream,
                       info, om_w0, om_b0, om_w1, om_b1, om);
    // K3: 32768 elements, 64 per block (1 wave) -> 512 blocks
    hipLaunchKernelGGL(k3_rho_cal, dim3(512), dim3(64), 0, stream,
                       means, om, endi, rw0, rb0, rw1, rb1, rw2, rb2,
                       cw0, cb0, cw1, cb1, cw2, cb2, mlog, out);
}

// Round 3
// 530.469 us; speedup vs baseline: 1.0046x; 1.0046x over previous
//
#include <hip/hip_runtime.h>
#include <math.h>

#define NB 32768          // B
#define NSEG 65536        // 2*B
#define NRF 11            // read features
#define NIF 9             // info features

// ---------------------------------------------------------------------------
// K1: per-read phi MLP (11 -> 64 relu -> 64 sigmoid) + segment mean.
// One wave per segment (8 segments per wave). lane = output feature.
// Weights held per-lane in VGPRs; read features via wave-uniform loads;
// hidden layer broadcast through per-wave LDS (double-buffered, float4 reads).
// Layer-2 accumulation split into 4 partials for ILP.
// ---------------------------------------------------------------------------
__global__ __launch_bounds__(256) void k1_phi_segmean(
    const float* __restrict__ reads,
    const int* __restrict__ endi,
    const float* __restrict__ w0, const float* __restrict__ b0,
    const float* __restrict__ w1, const float* __restrict__ b1,
    float* __restrict__ means)
{
    __shared__ float hbuf[4][2][64];   // [wave][parity][feature]
    const int lane = threadIdx.x & 63;
    const int wid  = threadIdx.x >> 6;
    const int wg   = __builtin_amdgcn_readfirstlane((int)(blockIdx.x * 4 + wid));

    float w0c[NRF];
#pragma unroll
    for (int k = 0; k < NRF; ++k) w0c[k] = w0[k * 64 + lane];
    float w1c[64];
#pragma unroll
    for (int i = 0; i < 64; ++i) w1c[i] = w1[i * 64 + lane];
    const float b0l = b0[lane];
    const float b1l = b1[lane];

    for (int i = 0; i < 8; ++i) {
        const int s = wg * 8 + i;
        const int r1 = endi[s];
        const int r0 = (s == 0) ? 0 : endi[s - 1];
        float acc = 0.f;
        for (int r = r0; r < r1; ++r) {
            const float* __restrict__ x = reads + (size_t)r * NRF;  // wave-uniform addr
            float h = b0l;
#pragma unroll
            for (int k = 0; k < NRF; ++k) h = fmaf(x[k], w0c[k], h);
            h = fmaxf(h, 0.f);
            const int p = r & 1;
            hbuf[wid][p][lane] = h;
            float o0 = b1l, o1 = 0.f, o2 = 0.f, o3 = 0.f;
            const float4* h4 = (const float4*)(&hbuf[wid][p][0]);
#pragma unroll
            for (int q = 0; q < 4; ++q) {
                float4 a = h4[q], bq = h4[q + 4], cq = h4[q + 8], dq = h4[q + 12];
                o0 = fmaf(a.x,  w1c[4*q+0],  o0);
                o0 = fmaf(a.y,  w1c[4*q+1],  o0);
                o0 = fmaf(a.z,  w1c[4*q+2],  o0);
                o0 = fmaf(a.w,  w1c[4*q+3],  o0);
                o1 = fmaf(bq.x, w1c[16+4*q+0], o1);
                o1 = fmaf(bq.y, w1c[16+4*q+1], o1);
                o1 = fmaf(bq.z, w1c[16+4*q+2], o1);
                o1 = fmaf(bq.w, w1c[16+4*q+3], o1);
                o2 = fmaf(cq.x, w1c[32+4*q+0], o2);
                o2 = fmaf(cq.y, w1c[32+4*q+1], o2);
                o2 = fmaf(cq.z, w1c[32+4*q+2], o2);
                o2 = fmaf(cq.w, w1c[32+4*q+3], o2);
                o3 = fmaf(dq.x, w1c[48+4*q+0], o3);
                o3 = fmaf(dq.y, w1c[48+4*q+1], o3);
                o3 = fmaf(dq.z, w1c[48+4*q+2], o3);
                o3 = fmaf(dq.w, w1c[48+4*q+3], o3);
            }
            const float o = (o0 + o1) + (o2 + o3);
            acc += 1.f / (1.f + __expf(-o));
        }
        means[(size_t)s * 64 + lane] = acc / (float)(r1 - r0);
    }
}

// ---------------------------------------------------------------------------
// K2: omega MLP on info (9 -> 64 relu -> 64 sigmoid). Wave per 8 rows.
// ---------------------------------------------------------------------------
__global__ __launch_bounds__(256) void k2_omega(
    const float* __restrict__ info,
    const float* __restrict__ w0, const float* __restrict__ b0,
    const float* __restrict__ w1, const float* __restrict__ b1,
    float* __restrict__ om)
{
    __shared__ float hbuf[4][64];
    const int lane = threadIdx.x & 63;
    const int wid  = threadIdx.x >> 6;
    const int wg   = __builtin_amdgcn_readfirstlane((int)(blockIdx.x * 4 + wid));

    float w0c[NIF];
#pragma unroll
    for (int k = 0; k < NIF; ++k) w0c[k] = w0[k * 64 + lane];
    float w1c[64];
#pragma unroll
    for (int i = 0; i < 64; ++i) w1c[i] = w1[i * 64 + lane];
    const float b0l = b0[lane];
    const float b1l = b1[lane];

    for (int i = 0; i < 8; ++i) {
        const int b = wg * 8 + i;
        const float* __restrict__ x = info + (size_t)b * NIF;  // wave-uniform
        float h = b0l;
#pragma unroll
        for (int k = 0; k < NIF; ++k) h = fmaf(x[k], w0c[k], h);
        h = fmaxf(h, 0.f);
        hbuf[wid][lane] = h;
        float o = b1l;
        const float4* h4 = (const float4*)(&hbuf[wid][0]);
#pragma unroll
        for (int q = 0; q < 16; ++q) {
            float4 hv = h4[q];
            o = fmaf(hv.x, w1c[4 * q + 0], o);
            o = fmaf(hv.y, w1c[4 * q + 1], o);
            o = fmaf(hv.z, w1c[4 * q + 2], o);
            o = fmaf(hv.w, w1c[4 * q + 3], o);
        }
        om[(size_t)b * 64 + lane] = 1.f / (1.f + __expf(-o));
    }
}

// ---------------------------------------------------------------------------
// K3: rho MLP (192 -> 128 relu -> 64 relu -> 1) + cal MLP + tanh clamp.
// Block = 256 threads (4 waves) handles 64 rows (lane = row).
// Wave w computes j-slice [w*32, w*32+32) of layer 0 and [w*16, w*16+16) of
// layer 1; activations exchanged via padded LDS (2-way bank aliasing = free).
// 512 blocks x 4 waves = 2048 waves -> 2 waves/SIMD on all CUs.
// ---------------------------------------------------------------------------
__global__ __launch_bounds__(256) void k3_rho_cal(
    const float* __restrict__ means, const float* __restrict__ om,
    const int* __restrict__ endi,
    const float* __restrict__ rw0, const float* __restrict__ rb0,
    const float* __restrict__ rw1, const float* __restrict__ rb1,
    const float* __restrict__ rw2, const float* __restrict__ rb2,
    const float* __restrict__ cw0, const float* __restrict__ cb0,
    const float* __restrict__ cw1, const float* __restrict__ cb1,
    const float* __restrict__ cw2, const float* __restrict__ cb2,
    const float* __restrict__ max_logit,
    float* __restrict__ out)
{
    __shared__ float xt[64 * 65];    // x chunk tile / later h2 buffer
    __shared__ float h1[64 * 129];   // layer-0 output, padded
    const int lane = threadIdx.x & 63;
    const int wid  = threadIdx.x >> 6;
    const int b0i  = blockIdx.x * 64;
    const int b    = b0i + lane;

    // ---- layer 0: acc[jj] for j = wid*32 + jj -------------------------------
    const int jbase = wid * 32;
    float acc[32];
#pragma unroll
    for (int jj = 0; jj < 32; ++jj) acc[jj] = rb0[jbase + jj];

    for (int c = 0; c < 3; ++c) {
        const float* __restrict__ src =
            (c == 0) ? means + (size_t)b0i * 64 :
            (c == 1) ? means + (size_t)(NB + b0i) * 64 :
                       om    + (size_t)b0i * 64;
        __syncthreads();   // previous users of xt done
#pragma unroll
        for (int it = 0; it < 16; ++it) {
            const int row = it * 4 + wid;
            xt[row * 65 + lane] = src[(size_t)row * 64 + lane];
        }
        __syncthreads();
        for (int k = 0; k < 64; ++k) {
            const float xk = xt[lane * 65 + k];
            const float* __restrict__ w = rw0 + (size_t)(c * 64 + k) * 128 + jbase; // uniform
#pragma unroll
            for (int jj = 0; jj < 32; ++jj) acc[jj] = fmaf(xk, w[jj], acc[jj]);
        }
    }
#pragma unroll
    for (int jj = 0; jj < 32; ++jj)
        h1[lane * 129 + jbase + jj] = fmaxf(acc[jj], 0.f);
    __syncthreads();

    // ---- layer 1: j2 = wid*16 + jj ------------------------------------------
    const int j2base = wid * 16;
    float acc2[16];
#pragma unroll
    for (int jj = 0; jj < 16; ++jj) acc2[jj] = rb1[j2base + jj];
    for (int i = 0; i < 128; ++i) {
        const float a = h1[lane * 129 + i];
        const float* __restrict__ w = rw1 + (size_t)i * 64 + j2base;  // uniform
#pragma unroll
        for (int jj = 0; jj < 16; ++jj) acc2[jj] = fmaf(a, w[jj], acc2[jj]);
    }
    __syncthreads();   // everyone done reading xt's previous contents
#pragma unroll
    for (int jj = 0; jj < 16; ++jj)
        xt[lane * 65 + j2base + jj] = fmaxf(acc2[jj], 0.f);   // h2 in xt
    __syncthreads();

    // ---- layer 2 + calibration + clamp (wave 0 only) ------------------------
    if (wid == 0) {
        float l0 = rb2[0], l1 = 0.f, l2 = 0.f, l3 = 0.f;
#pragma unroll
        for (int j = 0; j < 16; ++j) {
            l0 = fmaf(xt[lane * 65 + j],      rw2[j],      l0);
            l1 = fmaf(xt[lane * 65 + 16 + j], rw2[16 + j], l1);
            l2 = fmaf(xt[lane * 65 + 32 + j], rw2[32 + j], l2);
            l3 = fmaf(xt[lane * 65 + 48 + j], rw2[48 + j], l3);
        }
        const float logit = (l0 + l1) + (l2 + l3);

        const int er1 = endi[b];
        const int er0 = (b == 0) ? 0 : endi[b - 1];
        const int ea1 = endi[NB + b];
        const int ea0 = endi[NB + b - 1];
        const float x0 = sqrtf((float)(ea1 - ea0));   // sqrt(eff_alt)
        const float x1 = sqrtf((float)(er1 - er0));   // sqrt(eff_ref)

        float t5[5];
#pragma unroll
        for (int m = 0; m < 5; ++m)
            t5[m] = fmaxf(cb0[m] + x0 * cw0[m] + x1 * cw0[5 + m], 0.f);
        float t5b[5];
#pragma unroll
        for (int m = 0; m < 5; ++m) {
            float v = cb1[m];
#pragma unroll
            for (int i = 0; i < 5; ++i) v = fmaf(t5[i], cw1[i * 5 + m], v);
            t5b[m] = fmaxf(v, 0.f);
        }
        float temp = cb2[0];
#pragma unroll
        for (int m = 0; m < 5; ++m) temp = fmaf(t5b[m], cw2[m], temp);

        const float ml = max_logit[0];
        out[b] = ml * tanhf((logit * temp) / ml);
    }
}

// ---------------------------------------------------------------------------
extern "C" void kernel_launch(void* const* d_in, const int* in_sizes, int n_in,
                              void* d_out, int out_size, void* d_ws, size_t ws_size,
                              hipStream_t stream)
{
    const float* reads  = (const float*)d_in[0];
    const float* info   = (const float*)d_in[1];
    const int*   endi   = (const int*)d_in[2];       // int64 inputs arrive as int32
    const float* phi_w0 = (const float*)d_in[3];
    const float* phi_b0 = (const float*)d_in[4];
    const float* phi_w1 = (const float*)d_in[5];
    const float* phi_b1 = (const float*)d_in[6];
    const float* om_w0  = (const float*)d_in[7];
    const float* om_b0  = (const float*)d_in[8];
    const float* om_w1  = (const float*)d_in[9];
    const float* om_b1  = (const float*)d_in[10];
    const float* rw0    = (const float*)d_in[11];
    const float* rb0    = (const float*)d_in[12];
    const float* rw1    = (const float*)d_in[13];
    const float* rb1    = (const float*)d_in[14];
    const float* rw2    = (const float*)d_in[15];
    const float* rb2    = (const float*)d_in[16];
    const float* cw0    = (const float*)d_in[17];
    const float* cb0    = (const float*)d_in[18];
    const float* cw1    = (const float*)d_in[19];
    const float* cb1    = (const float*)d_in[20];
    const float* cw2    = (const float*)d_in[21];
    const float* cb2    = (const float*)d_in[22];
    const float* mlog   = (const float*)d_in[23];

    float* means = (float*)d_ws;                       // 65536*64 fp32 = 16.78 MB
    float* om    = means + (size_t)NSEG * 64;          // 32768*64 fp32 =  8.39 MB
    float* out   = (float*)d_out;

    // K1: 65536 segments, 8 per wave, 4 waves/block -> 2048 blocks
    hipLaunchKernelGGL(k1_phi_segmean, dim3(2048), dim3(256), 0, stream,
                       reads, endi, phi_w0, phi_b0, phi_w1, phi_b1, means);
    // K2: 32768 rows, 8 per wave, 4 waves/block -> 1024 blocks
    hipLaunchKernelGGL(k2_omega, dim3(1024), dim3(256), 0, stream,
                       info, om_w0, om_b0, om_w1, om_b1, om);
    // K3: 64 rows per block, 4 waves -> 512 blocks x 256 threads
    hipLaunchKernelGGL(k3_rho_cal, dim3(512), dim3(256), 0, stream,
                       means, om, endi, rw0, rb0, rw1, rb1, rw2, rb2,
                       cw0, cb0, cw1, cb1, cw2, cb2, mlog, out);
}

// Round 4
// 237.966 us; speedup vs baseline: 2.2393x; 2.2292x over previous
//
#include <hip/hip_runtime.h>
#include <hip/hip_bf16.h>
#include <math.h>

#define NB 32768          // B
#define NSEG 65536        // 2*B
#define NRF 11            // read features
#define NIF 9             // info features

typedef __attribute__((ext_vector_type(8))) short bf16x8;
typedef __attribute__((ext_vector_type(4))) float f32x4;

__device__ __forceinline__ short to_bf(float f) {
    __hip_bfloat16 h = __float2bfloat16(f);   // RNE
    return *reinterpret_cast<short*>(&h);
}

// ---------------------------------------------------------------------------
// K1: fused phi MLP (11 -> 64 relu -> 64 sigmoid) + segment mean, via bf16
// MFMA (fp32 accumulate).  Each block handles 16 segments; each segment gets
// its own 16-row MFMA tile(s) (count<=32 -> 1 or 2 tiles), zero-padded rows
// masked out in the epilogue so the segment sum is a masked column sum.
// Wave w handles segments w*4 .. w*4+3 of the block (sums stay in registers).
//
// Fragment layouts (gfx950, mfma_f32_16x16x32_bf16):
//   A: row = lane&15, k = 8*(lane>>4)+e    (8 bf16 per lane)
//   B: col = lane&15, k = 8*(lane>>4)+e
//   C/D: col = lane&15, row = 4*(lane>>4)+reg   [verified m89]
// ---------------------------------------------------------------------------
__global__ __launch_bounds__(256, 2) void k1_phi_mfma(
    const float* __restrict__ reads,
    const int* __restrict__ endi,
    const float* __restrict__ w0, const float* __restrict__ b0,
    const float* __restrict__ w1, const float* __restrict__ b1,
    float* __restrict__ means)
{
    __shared__ short XA[512][16];    // 16 KB  X tile, bf16, k padded 11..15 = 0
    __shared__ short W0T[64][24];    //  3 KB  W0T[col][k]  (k<11 real)
    __shared__ short W1T[64][72];    //  9.2KB W1T[col][k]  k=0..63, 144B rows
    __shared__ short HB[4][16][72];  //  9.2KB per-wave H tile, 144B rows
    __shared__ float BIAS[128];      //  b0[64], b1[64]
    __shared__ int   smeta[32];      //  segstart[16], segcnt[16]

    const int tid  = threadIdx.x;
    const int lane = tid & 63;
    const int w    = tid >> 6;
    const int lg   = lane >> 4;        // 0..3
    const int lr   = lane & 15;        // 0..15
    const int k0   = lg * 8;

    // ---- phase 0: segment metadata ------------------------------------------
    if (tid < 16) {
        const int ss = blockIdx.x * 16 + tid;
        const int e1 = endi[ss];
        const int e0 = (ss == 0) ? 0 : endi[ss - 1];
        smeta[tid]      = e0;
        smeta[16 + tid] = e1 - e0;
    }
    __syncthreads();

    // ---- phase 1: stage weights + X -----------------------------------------
    for (int i = tid; i < 64 * 16; i += 256) {       // W0T
        const int col = i >> 4, k = i & 15;
        W0T[col][k] = (k < NRF) ? to_bf(w0[k * 64 + col]) : (short)0;
    }
    for (int i = tid; i < 64 * 64; i += 256) {       // W1T
        const int col = i >> 6, k = i & 63;
        W1T[col][k] = to_bf(w1[k * 64 + col]);
    }
    if (tid < 64)              BIAS[tid]      = b0[tid];
    else if (tid < 128)        BIAS[tid]      = b1[tid - 64];

    for (int rr = tid; rr < 512; rr += 256) {        // X rows (2 per thread)
        const int ls = rr >> 5, j = rr & 31;
        const int cnt = smeta[16 + ls];
        if (j < cnt) {
            const float* __restrict__ xp = reads + (size_t)(smeta[ls] + j) * NRF;
#pragma unroll
            for (int k = 0; k < NRF; ++k) XA[rr][k] = to_bf(xp[k]);
#pragma unroll
            for (int k = NRF; k < 16; ++k) XA[rr][k] = 0;
        } else {
#pragma unroll
            for (int k = 0; k < 16; ++k) XA[rr][k] = 0;
        }
    }
    __syncthreads();

    // ---- preload weight fragments (register-resident) -----------------------
    bf16x8 bW0[4];                       // layer-1 B frags (k>=16 -> zero)
#pragma unroll
    for (int nt = 0; nt < 4; ++nt) {
        bf16x8 z = {0, 0, 0, 0, 0, 0, 0, 0};
        if (lg < 2) z = *(const bf16x8*)&W0T[nt * 16 + lr][k0];
        bW0[nt] = z;
    }
    bf16x8 bW1[4][2];                    // layer-2 B frags, 2 K-steps
#pragma unroll
    for (int nt = 0; nt < 4; ++nt)
#pragma unroll
        for (int ks = 0; ks < 2; ++ks)
            bW1[nt][ks] = *(const bf16x8*)&W1T[nt * 16 + lr][ks * 32 + k0];
    float bias0[4], bias1[4];
#pragma unroll
    for (int nt = 0; nt < 4; ++nt) {
        bias0[nt] = BIAS[nt * 16 + lr];
        bias1[nt] = BIAS[64 + nt * 16 + lr];
    }

    // ---- main loop: 4 segments per wave -------------------------------------
    for (int q = 0; q < 4; ++q) {
        const int ls  = w * 4 + q;
        const int cnt = smeta[16 + ls];
        const int ntl = (cnt + 15) >> 4;            // 1 or 2 tiles
        float segsum[4] = {0.f, 0.f, 0.f, 0.f};

        for (int tt = 0; tt < ntl; ++tt) {
            const int rowbase = ls * 32 + tt * 16;
            // layer 1: H = X * W0
            bf16x8 a1 = {0, 0, 0, 0, 0, 0, 0, 0};
            if (lg < 2) a1 = *(const bf16x8*)&XA[rowbase + lr][k0];
            f32x4 c1[4];
#pragma unroll
            for (int nt = 0; nt < 4; ++nt) {
                f32x4 z = {0.f, 0.f, 0.f, 0.f};
                c1[nt] = __builtin_amdgcn_mfma_f32_16x16x32_bf16(a1, bW0[nt], z, 0, 0, 0);
            }
            // bias + relu -> HB (bf16), per-wave buffer: no barrier needed
#pragma unroll
            for (int nt = 0; nt < 4; ++nt)
#pragma unroll
                for (int r = 0; r < 4; ++r) {
                    const float h = fmaxf(c1[nt][r] + bias0[nt], 0.f);
                    HB[w][4 * lg + r][nt * 16 + lr] = to_bf(h);
                }
            // layer 2: O = H * W1   (two K=32 steps)
            const bf16x8 a2a = *(const bf16x8*)&HB[w][lr][k0];
            const bf16x8 a2b = *(const bf16x8*)&HB[w][lr][32 + k0];
            f32x4 c2[4];
#pragma unroll
            for (int nt = 0; nt < 4; ++nt) {
                f32x4 z = {0.f, 0.f, 0.f, 0.f};
                f32x4 t = __builtin_amdgcn_mfma_f32_16x16x32_bf16(a2a, bW1[nt][0], z, 0, 0, 0);
                c2[nt]  = __builtin_amdgcn_mfma_f32_16x16x32_bf16(a2b, bW1[nt][1], t, 0, 0, 0);
            }
            // sigmoid + row-mask + column sum
            const int rowg = tt * 16 + 4 * lg;      // row within segment
#pragma unroll
            for (int nt = 0; nt < 4; ++nt) {
                float s = 0.f;
#pragma unroll
                for (int r = 0; r < 4; ++r) {
                    const float p = 1.f / (1.f + __expf(-(c2[nt][r] + bias1[nt])));
                    s += (rowg + r < cnt) ? p : 0.f;
                }
                s += __shfl_xor(s, 16);
                s += __shfl_xor(s, 32);
                segsum[nt] += s;
            }
        }
        if (lg == 0) {
            const size_t sg = (size_t)blockIdx.x * 16 + ls;
            const float inv = 1.f / (float)cnt;
#pragma unroll
            for (int nt = 0; nt < 4; ++nt)
                means[sg * 64 + nt * 16 + lr] = segsum[nt] * inv;
        }
    }
}

// ---------------------------------------------------------------------------
// K2: omega MLP on info (9 -> 64 relu -> 64 sigmoid). Wave per 8 rows.
// ---------------------------------------------------------------------------
__global__ __launch_bounds__(256) void k2_omega(
    const float* __restrict__ info,
    const float* __restrict__ w0, const float* __restrict__ b0,
    const float* __restrict__ w1, const float* __restrict__ b1,
    float* __restrict__ om)
{
    __shared__ float hbuf[4][64];
    const int lane = threadIdx.x & 63;
    const int wid  = threadIdx.x >> 6;
    const int wg   = __builtin_amdgcn_readfirstlane((int)(blockIdx.x * 4 + wid));

    float w0c[NIF];
#pragma unroll
    for (int k = 0; k < NIF; ++k) w0c[k] = w0[k * 64 + lane];
    float w1c[64];
#pragma unroll
    for (int i = 0; i < 64; ++i) w1c[i] = w1[i * 64 + lane];
    const float b0l = b0[lane];
    const float b1l = b1[lane];

    for (int i = 0; i < 8; ++i) {
        const int b = wg * 8 + i;
        const float* __restrict__ x = info + (size_t)b * NIF;  // wave-uniform
        float h = b0l;
#pragma unroll
        for (int k = 0; k < NIF; ++k) h = fmaf(x[k], w0c[k], h);
        h = fmaxf(h, 0.f);
        hbuf[wid][lane] = h;
        float o = b1l;
        const float4* h4 = (const float4*)(&hbuf[wid][0]);
#pragma unroll
        for (int q = 0; q < 16; ++q) {
            float4 hv = h4[q];
            o = fmaf(hv.x, w1c[4 * q + 0], o);
            o = fmaf(hv.y, w1c[4 * q + 1], o);
            o = fmaf(hv.z, w1c[4 * q + 2], o);
            o = fmaf(hv.w, w1c[4 * q + 3], o);
        }
        om[(size_t)b * 64 + lane] = 1.f / (1.f + __expf(-o));
    }
}

// ---------------------------------------------------------------------------
// K3: rho MLP (192 -> 128 relu -> 64 relu -> 1) + cal MLP + tanh clamp.
// Block = 256 threads (4 waves) handles 64 rows (lane = row); wave w computes
// a j-slice of each layer, activations exchanged via padded LDS.
// ---------------------------------------------------------------------------
__global__ __launch_bounds__(256) void k3_rho_cal(
    const float* __restrict__ means, const float* __restrict__ om,
    const int* __restrict__ endi,
    const float* __restrict__ rw0, const float* __restrict__ rb0,
    const float* __restrict__ rw1, const float* __restrict__ rb1,
    const float* __restrict__ rw2, const float* __restrict__ rb2,
    const float* __restrict__ cw0, const float* __restrict__ cb0,
    const float* __restrict__ cw1, const float* __restrict__ cb1,
    const float* __restrict__ cw2, const float* __restrict__ cb2,
    const float* __restrict__ max_logit,
    float* __restrict__ out)
{
    __shared__ float xt[64 * 65];    // x chunk tile / later h2 buffer
    __shared__ float h1[64 * 129];   // layer-0 output, padded
    const int lane = threadIdx.x & 63;
    const int wid  = threadIdx.x >> 6;
    const int b0i  = blockIdx.x * 64;
    const int b    = b0i + lane;

    const int jbase = wid * 32;
    float acc[32];
#pragma unroll
    for (int jj = 0; jj < 32; ++jj) acc[jj] = rb0[jbase + jj];

    for (int c = 0; c < 3; ++c) {
        const float* __restrict__ src =
            (c == 0) ? means + (size_t)b0i * 64 :
            (c == 1) ? means + (size_t)(NB + b0i) * 64 :
                       om    + (size_t)b0i * 64;
        __syncthreads();
#pragma unroll
        for (int it = 0; it < 16; ++it) {
            const int row = it * 4 + wid;
            xt[row * 65 + lane] = src[(size_t)row * 64 + lane];
        }
        __syncthreads();
        for (int k = 0; k < 64; ++k) {
            const float xk = xt[lane * 65 + k];
            const float* __restrict__ wv = rw0 + (size_t)(c * 64 + k) * 128 + jbase;
#pragma unroll
            for (int jj = 0; jj < 32; ++jj) acc[jj] = fmaf(xk, wv[jj], acc[jj]);
        }
    }
#pragma unroll
    for (int jj = 0; jj < 32; ++jj)
        h1[lane * 129 + jbase + jj] = fmaxf(acc[jj], 0.f);
    __syncthreads();

    const int j2base = wid * 16;
    float acc2[16];
#pragma unroll
    for (int jj = 0; jj < 16; ++jj) acc2[jj] = rb1[j2base + jj];
    for (int i = 0; i < 128; ++i) {
        const float a = h1[lane * 129 + i];
        const float* __restrict__ wv = rw1 + (size_t)i * 64 + j2base;
#pragma unroll
        for (int jj = 0; jj < 16; ++jj) acc2[jj] = fmaf(a, wv[jj], acc2[jj]);
    }
    __syncthreads();
#pragma unroll
    for (int jj = 0; jj < 16; ++jj)
        xt[lane * 65 + j2base + jj] = fmaxf(acc2[jj], 0.f);
    __syncthreads();

    if (wid == 0) {
        float l0 = rb2[0], l1 = 0.f, l2 = 0.f, l3 = 0.f;
#pragma unroll
        for (int j = 0; j < 16; ++j) {
            l0 = fmaf(xt[lane * 65 + j],      rw2[j],      l0);
            l1 = fmaf(xt[lane * 65 + 16 + j], rw2[16 + j], l1);
            l2 = fmaf(xt[lane * 65 + 32 + j], rw2[32 + j], l2);
            l3 = fmaf(xt[lane * 65 + 48 + j], rw2[48 + j], l3);
        }
        const float logit = (l0 + l1) + (l2 + l3);

        const int er1 = endi[b];
        const int er0 = (b == 0) ? 0 : endi[b - 1];
        const int ea1 = endi[NB + b];
        const int ea0 = endi[NB + b - 1];
        const float x0 = sqrtf((float)(ea1 - ea0));
        const float x1 = sqrtf((float)(er1 - er0));

        float t5[5];
#pragma unroll
        for (int m = 0; m < 5; ++m)
            t5[m] = fmaxf(cb0[m] + x0 * cw0[m] + x1 * cw0[5 + m], 0.f);
        float t5b[5];
#pragma unroll
        for (int m = 0; m < 5; ++m) {
            float v = cb1[m];
#pragma unroll
            for (int i = 0; i < 5; ++i) v = fmaf(t5[i], cw1[i * 5 + m], v);
            t5b[m] = fmaxf(v, 0.f);
        }
        float temp = cb2[0];
#pragma unroll
        for (int m = 0; m < 5; ++m) temp = fmaf(t5b[m], cw2[m], temp);

        const float ml = max_logit[0];
        out[b] = ml * tanhf((logit * temp) / ml);
    }
}

// ---------------------------------------------------------------------------
extern "C" void kernel_launch(void* const* d_in, const int* in_sizes, int n_in,
                              void* d_out, int out_size, void* d_ws, size_t ws_size,
                              hipStream_t stream)
{
    const float* reads  = (const float*)d_in[0];
    const float* info   = (const float*)d_in[1];
    const int*   endi   = (const int*)d_in[2];       // int64 inputs arrive as int32
    const float* phi_w0 = (const float*)d_in[3];
    const float* phi_b0 = (const float*)d_in[4];
    const float* phi_w1 = (const float*)d_in[5];
    const float* phi_b1 = (const float*)d_in[6];
    const float* om_w0  = (const float*)d_in[7];
    const float* om_b0  = (const float*)d_in[8];
    const float* om_w1  = (const float*)d_in[9];
    const float* om_b1  = (const float*)d_in[10];
    const float* rw0    = (const float*)d_in[11];
    const float* rb0    = (const float*)d_in[12];
    const float* rw1    = (const float*)d_in[13];
    const float* rb1    = (const float*)d_in[14];
    const float* rw2    = (const float*)d_in[15];
    const float* rb2    = (const float*)d_in[16];
    const float* cw0    = (const float*)d_in[17];
    const float* cb0    = (const float*)d_in[18];
    const float* cw1    = (const float*)d_in[19];
    const float* cb1    = (const float*)d_in[20];
    const float* cw2    = (const float*)d_in[21];
    const float* cb2    = (const float*)d_in[22];
    const float* mlog   = (const float*)d_in[23];

    float* means = (float*)d_ws;                       // 65536*64 fp32 = 16.78 MB
    float* om    = means + (size_t)NSEG * 64;          // 32768*64 fp32 =  8.39 MB
    float* out   = (float*)d_out;

    // K1: 16 segments per block -> 4096 blocks x 256 threads
    hipLaunchKernelGGL(k1_phi_mfma, dim3(4096), dim3(256), 0, stream,
                       reads, endi, phi_w0, phi_b0, phi_w1, phi_b1, means);
    // K2: 32768 rows, 8 per wave, 4 waves/block -> 1024 blocks
    hipLaunchKernelGGL(k2_omega, dim3(1024), dim3(256), 0, stream,
                       info, om_w0, om_b0, om_w1, om_b1, om);
    // K3: 64 rows per block, 4 waves -> 512 blocks x 256 threads
    hipLaunchKernelGGL(k3_rho_cal, dim3(512), dim3(256), 0, stream,
                       means, om, endi, rw0, rb0, rw1, rb1, rw2, rb2,
                       cw0, cb0, cw1, cb1, cw2, cb2, mlog, out);
}

// Round 5
// 136.950 us; speedup vs baseline: 3.8911x; 1.7376x over previous
//
#include <hip/hip_runtime.h>
#include <hip/hip_bf16.h>
#include <math.h>

#define NB 32768          // B
#define NSEG 65536        // 2*B
#define NRF 11            // read features
#define NIF 9             // info features

typedef __attribute__((ext_vector_type(8))) short bf16x8;
typedef __attribute__((ext_vector_type(4))) float f32x4;

__device__ __forceinline__ short to_bf(float f) {
    __hip_bfloat16 h = __float2bfloat16(f);   // RNE
    return *reinterpret_cast<short*>(&h);
}
__device__ __forceinline__ float bf2f(short s) {
    __hip_bfloat16 h = *reinterpret_cast<__hip_bfloat16*>(&s);
    return __bfloat162float(h);
}

// ---------------------------------------------------------------------------
// K0: prep rho weights into transposed split-bf16 planes in ws.
//   W0T_{hi,lo}[col][k] : col<128, k<192   (B-frag layout for layer 0)
//   W1T_{hi,lo}[col][k] : col<64,  k<128   (B-frag layout for layer 1)
// ---------------------------------------------------------------------------
__global__ __launch_bounds__(256) void k0_prep(
    const float* __restrict__ rw0, const float* __restrict__ rw1,
    short* __restrict__ w0th, short* __restrict__ w0tl,
    short* __restrict__ w1th, short* __restrict__ w1tl)
{
    const int idx = blockIdx.x * 256 + threadIdx.x;
    if (idx < 192 * 128) {
        const int k = idx >> 7, col = idx & 127;      // rw0[k][col]
        const float v = rw0[idx];
        const short hi = to_bf(v);
        const short lo = to_bf(v - bf2f(hi));
        w0th[col * 192 + k] = hi;
        w0tl[col * 192 + k] = lo;
    }
    if (idx < 128 * 64) {
        const int k = idx >> 6, col = idx & 63;       // rw1[k][col]
        const float v = rw1[idx];
        const short hi = to_bf(v);
        const short lo = to_bf(v - bf2f(hi));
        w1th[col * 128 + k] = hi;
        w1tl[col * 128 + k] = lo;
    }
}

// ---------------------------------------------------------------------------
// K1: fused phi MLP (11 -> 64 relu -> 64 sigmoid) + segment mean, bf16 MFMA.
// (unchanged from round 4 — verified)
// ---------------------------------------------------------------------------
__global__ __launch_bounds__(256, 2) void k1_phi_mfma(
    const float* __restrict__ reads,
    const int* __restrict__ endi,
    const float* __restrict__ w0, const float* __restrict__ b0,
    const float* __restrict__ w1, const float* __restrict__ b1,
    float* __restrict__ means)
{
    __shared__ short XA[512][16];
    __shared__ short W0T[64][24];
    __shared__ short W1T[64][72];
    __shared__ short HB[4][16][72];
    __shared__ float BIAS[128];
    __shared__ int   smeta[32];

    const int tid  = threadIdx.x;
    const int lane = tid & 63;
    const int w    = tid >> 6;
    const int lg   = lane >> 4;
    const int lr   = lane & 15;
    const int k0   = lg * 8;

    if (tid < 16) {
        const int ss = blockIdx.x * 16 + tid;
        const int e1 = endi[ss];
        const int e0 = (ss == 0) ? 0 : endi[ss - 1];
        smeta[tid]      = e0;
        smeta[16 + tid] = e1 - e0;
    }
    __syncthreads();

    for (int i = tid; i < 64 * 16; i += 256) {
        const int col = i >> 4, k = i & 15;
        W0T[col][k] = (k < NRF) ? to_bf(w0[k * 64 + col]) : (short)0;
    }
    for (int i = tid; i < 64 * 64; i += 256) {
        const int col = i >> 6, k = i & 63;
        W1T[col][k] = to_bf(w1[k * 64 + col]);
    }
    if (tid < 64)              BIAS[tid] = b0[tid];
    else if (tid < 128)        BIAS[tid] = b1[tid - 64];

    for (int rr = tid; rr < 512; rr += 256) {
        const int ls = rr >> 5, j = rr & 31;
        const int cnt = smeta[16 + ls];
        if (j < cnt) {
            const float* __restrict__ xp = reads + (size_t)(smeta[ls] + j) * NRF;
#pragma unroll
            for (int k = 0; k < NRF; ++k) XA[rr][k] = to_bf(xp[k]);
#pragma unroll
            for (int k = NRF; k < 16; ++k) XA[rr][k] = 0;
        } else {
#pragma unroll
            for (int k = 0; k < 16; ++k) XA[rr][k] = 0;
        }
    }
    __syncthreads();

    bf16x8 bW0[4];
#pragma unroll
    for (int nt = 0; nt < 4; ++nt) {
        bf16x8 z = {0, 0, 0, 0, 0, 0, 0, 0};
        if (lg < 2) z = *(const bf16x8*)&W0T[nt * 16 + lr][k0];
        bW0[nt] = z;
    }
    bf16x8 bW1[4][2];
#pragma unroll
    for (int nt = 0; nt < 4; ++nt)
#pragma unroll
        for (int ks = 0; ks < 2; ++ks)
            bW1[nt][ks] = *(const bf16x8*)&W1T[nt * 16 + lr][ks * 32 + k0];
    float bias0[4], bias1[4];
#pragma unroll
    for (int nt = 0; nt < 4; ++nt) {
        bias0[nt] = BIAS[nt * 16 + lr];
        bias1[nt] = BIAS[64 + nt * 16 + lr];
    }

    for (int q = 0; q < 4; ++q) {
        const int ls  = w * 4 + q;
        const int cnt = smeta[16 + ls];
        const int ntl = (cnt + 15) >> 4;
        float segsum[4] = {0.f, 0.f, 0.f, 0.f};

        for (int tt = 0; tt < ntl; ++tt) {
            const int rowbase = ls * 32 + tt * 16;
            bf16x8 a1 = {0, 0, 0, 0, 0, 0, 0, 0};
            if (lg < 2) a1 = *(const bf16x8*)&XA[rowbase + lr][k0];
            f32x4 c1[4];
#pragma unroll
            for (int nt = 0; nt < 4; ++nt) {
                f32x4 z = {0.f, 0.f, 0.f, 0.f};
                c1[nt] = __builtin_amdgcn_mfma_f32_16x16x32_bf16(a1, bW0[nt], z, 0, 0, 0);
            }
#pragma unroll
            for (int nt = 0; nt < 4; ++nt)
#pragma unroll
                for (int r = 0; r < 4; ++r) {
                    const float h = fmaxf(c1[nt][r] + bias0[nt], 0.f);
                    HB[w][4 * lg + r][nt * 16 + lr] = to_bf(h);
                }
            const bf16x8 a2a = *(const bf16x8*)&HB[w][lr][k0];
            const bf16x8 a2b = *(const bf16x8*)&HB[w][lr][32 + k0];
            f32x4 c2[4];
#pragma unroll
            for (int nt = 0; nt < 4; ++nt) {
                f32x4 z = {0.f, 0.f, 0.f, 0.f};
                f32x4 t = __builtin_amdgcn_mfma_f32_16x16x32_bf16(a2a, bW1[nt][0], z, 0, 0, 0);
                c2[nt]  = __builtin_amdgcn_mfma_f32_16x16x32_bf16(a2b, bW1[nt][1], t, 0, 0, 0);
            }
            const int rowg = tt * 16 + 4 * lg;
#pragma unroll
            for (int nt = 0; nt < 4; ++nt) {
                float s = 0.f;
#pragma unroll
                for (int r = 0; r < 4; ++r) {
                    const float p = 1.f / (1.f + __expf(-(c2[nt][r] + bias1[nt])));
                    s += (rowg + r < cnt) ? p : 0.f;
                }
                s += __shfl_xor(s, 16);
                s += __shfl_xor(s, 32);
                segsum[nt] += s;
            }
        }
        if (lg == 0) {
            const size_t sg = (size_t)blockIdx.x * 16 + ls;
            const float inv = 1.f / (float)cnt;
#pragma unroll
            for (int nt = 0; nt < 4; ++nt)
                means[sg * 64 + nt * 16 + lr] = segsum[nt] * inv;
        }
    }
}

// ---------------------------------------------------------------------------
// K2: omega MLP on info (9 -> 64 relu -> 64 sigmoid). (unchanged)
// ---------------------------------------------------------------------------
__global__ __launch_bounds__(256) void k2_omega(
    const float* __restrict__ info,
    const float* __restrict__ w0, const float* __restrict__ b0,
    const float* __restrict__ w1, const float* __restrict__ b1,
    float* __restrict__ om)
{
    __shared__ float hbuf[4][64];
    const int lane = threadIdx.x & 63;
    const int wid  = threadIdx.x >> 6;
    const int wg   = __builtin_amdgcn_readfirstlane((int)(blockIdx.x * 4 + wid));

    float w0c[NIF];
#pragma unroll
    for (int k = 0; k < NIF; ++k) w0c[k] = w0[k * 64 + lane];
    float w1c[64];
#pragma unroll
    for (int i = 0; i < 64; ++i) w1c[i] = w1[i * 64 + lane];
    const float b0l = b0[lane];
    const float b1l = b1[lane];

    for (int i = 0; i < 8; ++i) {
        const int b = wg * 8 + i;
        const float* __restrict__ x = info + (size_t)b * NIF;
        float h = b0l;
#pragma unroll
        for (int k = 0; k < NIF; ++k) h = fmaf(x[k], w0c[k], h);
        h = fmaxf(h, 0.f);
        hbuf[wid][lane] = h;
        float o = b1l;
        const float4* h4 = (const float4*)(&hbuf[wid][0]);
#pragma unroll
        for (int q = 0; q < 16; ++q) {
            float4 hv = h4[q];
            o = fmaf(hv.x, w1c[4 * q + 0], o);
            o = fmaf(hv.y, w1c[4 * q + 1], o);
            o = fmaf(hv.z, w1c[4 * q + 2], o);
            o = fmaf(hv.w, w1c[4 * q + 3], o);
        }
        om[(size_t)b * 64 + lane] = 1.f / (1.f + __expf(-o));
    }
}

// ---------------------------------------------------------------------------
// K3: rho MLP via split-bf16 MFMA (3-term: hh + lh + hl, ~fp32 accuracy).
// Block = 64 rows x 4 waves. Layer0: wave w owns cols [w*32,w*32+32).
// X staged per-64-k chunk as hi/lo bf16 in LDS; W frags read coalesced from
// the K0-transposed planes. Layer1: wave w owns cols [w*16,w*16+16).
// h2 exchanged via LDS (transposed); epilogue (layer2+cal+tanh) on wave 0.
// ---------------------------------------------------------------------------
__global__ __launch_bounds__(256) void k3_rho_mfma(
    const float* __restrict__ means, const float* __restrict__ om,
    const int* __restrict__ endi,
    const short* __restrict__ w0th, const short* __restrict__ w0tl,
    const short* __restrict__ w1th, const short* __restrict__ w1tl,
    const float* __restrict__ rb0, const float* __restrict__ rb1,
    const float* __restrict__ rw2, const float* __restrict__ rb2,
    const float* __restrict__ cw0, const float* __restrict__ cb0,
    const float* __restrict__ cw1, const float* __restrict__ cb1,
    const float* __restrict__ cw2, const float* __restrict__ cb2,
    const float* __restrict__ max_logit,
    float* __restrict__ out)
{
    // region A: X planes (2 x 64x72 shorts = 18432 B) later reused as h2T (64x68 f32 = 17408 B)
    // region B: H planes (2 x 64x136 shorts = 34816 B)
    __shared__ __align__(16) char smemA[18432];
    __shared__ __align__(16) char smemB[34816];
    short (*XH)[72]  = (short(*)[72])smemA;
    short (*XL)[72]  = (short(*)[72])(smemA + 9216);
    short (*HH)[136] = (short(*)[136])smemB;
    short (*HL)[136] = (short(*)[136])(smemB + 17408);
    float (*h2T)[68] = (float(*)[68])smemA;

    const int tid  = threadIdx.x;
    const int lane = tid & 63;
    const int w    = tid >> 6;        // wave 0..3
    const int lg   = lane >> 4;       // 0..3
    const int lr   = lane & 15;       // 0..15
    const int k0   = lg * 8;
    const int b0i  = blockIdx.x * 64;

    // ---- layer 0: C[64 x 128], wave w owns 2 col-tiles at wbase ------------
    const int wbase = w * 32;
    float bias0[2];
#pragma unroll
    for (int nt = 0; nt < 2; ++nt) bias0[nt] = rb0[wbase + nt * 16 + lr];

    f32x4 acc[4][2];
#pragma unroll
    for (int rt = 0; rt < 4; ++rt)
#pragma unroll
        for (int nt = 0; nt < 2; ++nt) acc[rt][nt] = (f32x4){0.f, 0.f, 0.f, 0.f};

    for (int c = 0; c < 3; ++c) {
        const float* __restrict__ src =
            (c == 0) ? means + (size_t)b0i * 64 :
            (c == 1) ? means + (size_t)(NB + b0i) * 64 :
                       om    + (size_t)b0i * 64;
        __syncthreads();   // previous chunk fully consumed
        for (int idx = tid; idx < 64 * 64; idx += 256) {
            const int row = idx >> 6, col = idx & 63;
            const float v = src[(size_t)row * 64 + col];
            const short hi = to_bf(v);
            const short lo = to_bf(v - bf2f(hi));
            XH[row][col] = hi;
            XL[row][col] = lo;
        }
        __syncthreads();

#pragma unroll
        for (int ks = 0; ks < 2; ++ks) {
            const int koff = c * 64 + ks * 32 + k0;
            bf16x8 Bh[2], Bl[2];
#pragma unroll
            for (int nt = 0; nt < 2; ++nt) {
                const int col = wbase + nt * 16 + lr;
                Bh[nt] = *(const bf16x8*)&w0th[(size_t)col * 192 + koff];
                Bl[nt] = *(const bf16x8*)&w0tl[(size_t)col * 192 + koff];
            }
#pragma unroll
            for (int rt = 0; rt < 4; ++rt) {
                const bf16x8 Ah = *(const bf16x8*)&XH[rt * 16 + lr][ks * 32 + k0];
                const bf16x8 Al = *(const bf16x8*)&XL[rt * 16 + lr][ks * 32 + k0];
#pragma unroll
                for (int nt = 0; nt < 2; ++nt) {
                    acc[rt][nt] = __builtin_amdgcn_mfma_f32_16x16x32_bf16(Ah, Bh[nt], acc[rt][nt], 0, 0, 0);
                    acc[rt][nt] = __builtin_amdgcn_mfma_f32_16x16x32_bf16(Al, Bh[nt], acc[rt][nt], 0, 0, 0);
                    acc[rt][nt] = __builtin_amdgcn_mfma_f32_16x16x32_bf16(Ah, Bl[nt], acc[rt][nt], 0, 0, 0);
                }
            }
        }
    }
    __syncthreads();   // all waves done reading X (region A free soon); HB write next
    // bias + relu + split -> H planes
#pragma unroll
    for (int rt = 0; rt < 4; ++rt)
#pragma unroll
        for (int nt = 0; nt < 2; ++nt)
#pragma unroll
            for (int r = 0; r < 4; ++r) {
                const int row = rt * 16 + 4 * lg + r;
                const int col = wbase + nt * 16 + lr;
                const float v = fmaxf(acc[rt][nt][r] + bias0[nt], 0.f);
                const short hi = to_bf(v);
                HH[row][col] = hi;
                HL[row][col] = to_bf(v - bf2f(hi));
            }
    __syncthreads();

    // ---- layer 1: C[64 x 64], wave w owns 1 col-tile at cbase --------------
    const int cbase = w * 16;
    const float bias1 = rb1[cbase + lr];
    f32x4 acc2[4];
#pragma unroll
    for (int rt = 0; rt < 4; ++rt) acc2[rt] = (f32x4){0.f, 0.f, 0.f, 0.f};

#pragma unroll
    for (int ks = 0; ks < 4; ++ks) {
        const int koff = ks * 32 + k0;
        const int col  = cbase + lr;
        const bf16x8 Bh = *(const bf16x8*)&w1th[(size_t)col * 128 + koff];
        const bf16x8 Bl = *(const bf16x8*)&w1tl[(size_t)col * 128 + koff];
#pragma unroll
        for (int rt = 0; rt < 4; ++rt) {
            const bf16x8 Ah = *(const bf16x8*)&HH[rt * 16 + lr][koff];
            const bf16x8 Al = *(const bf16x8*)&HL[rt * 16 + lr][koff];
            acc2[rt] = __builtin_amdgcn_mfma_f32_16x16x32_bf16(Ah, Bh, acc2[rt], 0, 0, 0);
            acc2[rt] = __builtin_amdgcn_mfma_f32_16x16x32_bf16(Al, Bh, acc2[rt], 0, 0, 0);
            acc2[rt] = __builtin_amdgcn_mfma_f32_16x16x32_bf16(Ah, Bl, acc2[rt], 0, 0, 0);
        }
    }
    // write h2 (relu) transposed into region A (X long dead)
#pragma unroll
    for (int rt = 0; rt < 4; ++rt)
#pragma unroll
        for (int r = 0; r < 4; ++r)
            h2T[cbase + lr][rt * 16 + 4 * lg + r] = fmaxf(acc2[rt][r] + bias1, 0.f);
    __syncthreads();

    // ---- layer 2 + calibration + clamp (wave 0, lane = row) ----------------
    if (w == 0) {
        const int b = b0i + lane;
        float l0 = rb2[0], l1 = 0.f, l2 = 0.f, l3 = 0.f;
#pragma unroll
        for (int j = 0; j < 16; ++j) {
            l0 = fmaf(h2T[j][lane],      rw2[j],      l0);
            l1 = fmaf(h2T[16 + j][lane], rw2[16 + j], l1);
            l2 = fmaf(h2T[32 + j][lane], rw2[32 + j], l2);
            l3 = fmaf(h2T[48 + j][lane], rw2[48 + j], l3);
        }
        const float logit = (l0 + l1) + (l2 + l3);

        const int er1 = endi[b];
        const int er0 = (b == 0) ? 0 : endi[b - 1];
        const int ea1 = endi[NB + b];
        const int ea0 = endi[NB + b - 1];
        const float x0 = sqrtf((float)(ea1 - ea0));   // sqrt(eff_alt)
        const float x1 = sqrtf((float)(er1 - er0));   // sqrt(eff_ref)

        float t5[5];
#pragma unroll
        for (int m = 0; m < 5; ++m)
            t5[m] = fmaxf(cb0[m] + x0 * cw0[m] + x1 * cw0[5 + m], 0.f);
        float t5b[5];
#pragma unroll
        for (int m = 0; m < 5; ++m) {
            float v = cb1[m];
#pragma unroll
            for (int i = 0; i < 5; ++i) v = fmaf(t5[i], cw1[i * 5 + m], v);
            t5b[m] = fmaxf(v, 0.f);
        }
        float temp = cb2[0];
#pragma unroll
        for (int m = 0; m < 5; ++m) temp = fmaf(t5b[m], cw2[m], temp);

        const float ml = max_logit[0];
        out[b] = ml * tanhf((logit * temp) / ml);
    }
}

// ---------------------------------------------------------------------------
extern "C" void kernel_launch(void* const* d_in, const int* in_sizes, int n_in,
                              void* d_out, int out_size, void* d_ws, size_t ws_size,
                              hipStream_t stream)
{
    const float* reads  = (const float*)d_in[0];
    const float* info   = (const float*)d_in[1];
    const int*   endi   = (const int*)d_in[2];       // int64 inputs arrive as int32
    const float* phi_w0 = (const float*)d_in[3];
    const float* phi_b0 = (const float*)d_in[4];
    const float* phi_w1 = (const float*)d_in[5];
    const float* phi_b1 = (const float*)d_in[6];
    const float* om_w0  = (const float*)d_in[7];
    const float* om_b0  = (const float*)d_in[8];
    const float* om_w1  = (const float*)d_in[9];
    const float* om_b1  = (const float*)d_in[10];
    const float* rw0    = (const float*)d_in[11];
    const float* rb0    = (const float*)d_in[12];
    const float* rw1    = (const float*)d_in[13];
    const float* rb1    = (const float*)d_in[14];
    const float* rw2    = (const float*)d_in[15];
    const float* rb2    = (const float*)d_in[16];
    const float* cw0    = (const float*)d_in[17];
    const float* cb0    = (const float*)d_in[18];
    const float* cw1    = (const float*)d_in[19];
    const float* cb1    = (const float*)d_in[20];
    const float* cw2    = (const float*)d_in[21];
    const float* cb2    = (const float*)d_in[22];
    const float* mlog   = (const float*)d_in[23];

    char* ws = (char*)d_ws;
    float* means = (float*)ws;                                   // 16,777,216 B
    float* om    = (float*)(ws + 16777216);                      //  8,388,608 B
    short* w0th  = (short*)(ws + 25165824);                      //     49,152 B
    short* w0tl  = (short*)(ws + 25165824 + 49152);              //     49,152 B
    short* w1th  = (short*)(ws + 25165824 + 98304);              //     16,384 B
    short* w1tl  = (short*)(ws + 25165824 + 114688);             //     16,384 B
    float* out   = (float*)d_out;

    // K0: weight transpose/split (96 blocks covers 24576 elements)
    hipLaunchKernelGGL(k0_prep, dim3(96), dim3(256), 0, stream,
                       rw0, rw1, w0th, w0tl, w1th, w1tl);
    // K1: 16 segments per block -> 4096 blocks
    hipLaunchKernelGGL(k1_phi_mfma, dim3(4096), dim3(256), 0, stream,
                       reads, endi, phi_w0, phi_b0, phi_w1, phi_b1, means);
    // K2: 32768 rows, 8 per wave, 4 waves/block -> 1024 blocks
    hipLaunchKernelGGL(k2_omega, dim3(1024), dim3(256), 0, stream,
                       info, om_w0, om_b0, om_w1, om_b1, om);
    // K3: 64 rows per block -> 512 blocks x 256 threads
    hipLaunchKernelGGL(k3_rho_mfma, dim3(512), dim3(256), 0, stream,
                       means, om, endi, w0th, w0tl, w1th, w1tl,
                       rb0, rb1, rw2, rb2,
                       cw0, cb0, cw1, cb1, cw2, cb2, mlog, out);
}

// Round 6
// 116.980 us; speedup vs baseline: 4.5554x; 1.1707x over previous
//
#include <hip/hip_runtime.h>
#include <hip/hip_bf16.h>
#include <math.h>

#define NB 32768          // B
#define NSEG 65536        // 2*B
#define NRF 11            // read features
#define NIF 9             // info features

typedef __attribute__((ext_vector_type(8))) short bf16x8;
typedef __attribute__((ext_vector_type(4))) float f32x4;

__device__ __forceinline__ short to_bf(float f) {
    __hip_bfloat16 h = __float2bfloat16(f);   // RNE
    return *reinterpret_cast<short*>(&h);
}
__device__ __forceinline__ float bf2f(short s) {
    __hip_bfloat16 h = *reinterpret_cast<__hip_bfloat16*>(&s);
    return __bfloat162float(h);
}

// ---------------------------------------------------------------------------
// K0: one-time weight prep into ws.
//  rho:  W0T_{hi,lo}[col][k] col<128,k<192 ; W1T_{hi,lo}[col][k] col<64,k<128
//  phi:  p_w0t[col][16] (k<11 real, rest 0) ; p_w1t[col][64]   (bf16, plain)
// ---------------------------------------------------------------------------
__global__ __launch_bounds__(256) void k0_prep(
    const float* __restrict__ rw0, const float* __restrict__ rw1,
    const float* __restrict__ pw0, const float* __restrict__ pw1,
    short* __restrict__ w0th, short* __restrict__ w0tl,
    short* __restrict__ w1th, short* __restrict__ w1tl,
    short* __restrict__ p_w0t, short* __restrict__ p_w1t)
{
    const int idx = blockIdx.x * 256 + threadIdx.x;
    if (idx < 192 * 128) {
        const int k = idx >> 7, col = idx & 127;      // rw0[k][col]
        const float v = rw0[idx];
        const short hi = to_bf(v);
        const short lo = to_bf(v - bf2f(hi));
        w0th[col * 192 + k] = hi;
        w0tl[col * 192 + k] = lo;
    }
    if (idx < 128 * 64) {
        const int k = idx >> 6, col = idx & 63;       // rw1[k][col]
        const float v = rw1[idx];
        const short hi = to_bf(v);
        const short lo = to_bf(v - bf2f(hi));
        w1th[col * 128 + k] = hi;
        w1tl[col * 128 + k] = lo;
    }
    if (idx < 64 * 16) {
        const int col = idx >> 4, k = idx & 15;
        p_w0t[idx] = (k < NRF) ? to_bf(pw0[k * 64 + col]) : (short)0;
    }
    if (idx < 64 * 64) {
        const int col = idx >> 6, k = idx & 63;
        p_w1t[idx] = to_bf(pw1[k * 64 + col]);
    }
}

// ---------------------------------------------------------------------------
// K1 v2: fused phi MLP + segment mean, bf16 MFMA, packed staging.
// Block = 16 consecutive segments = one contiguous `reads` range.
//  - X staged packed (coalesced float loads), 48B row stride, cols 11..15 = 0.
//  - layer 1 SWAPPED: D_nt = mfma(A=W0T frag, B=X frag) -> lane holds 4
//    consecutive H-cols per nt -> packed short4 ds_write_b64 into HB.
//  - layer 2 standard: A = H row frags from HB, B = p_w1t frags (registers).
//  - out-of-segment tile rows: clamped to valid packed rows (finite garbage),
//    masked post-sigmoid; segment sum via shfl_xor 16/32.
//  - wave w handles segments {w, w+4, w+8, w+12} (interleaved for balance).
// ---------------------------------------------------------------------------
__global__ __launch_bounds__(256, 4) void k1_phi_mfma2(
    const float* __restrict__ reads,
    const int* __restrict__ endi,
    const short* __restrict__ p_w0t, const short* __restrict__ p_w1t,
    const float* __restrict__ b0, const float* __restrict__ b1,
    float* __restrict__ means)
{
    __shared__ short XA[512][24];     // 24.6 KB packed X, bf16
    __shared__ short HB[4][16][72];   //  9.2 KB per-wave H tile (144B rows)
    __shared__ int   smeta[17];       // boundaries endi[s0-1 .. s0+15]

    const int tid  = threadIdx.x;
    const int lane = tid & 63;
    const int w    = tid >> 6;
    const int lg   = lane >> 4;       // 0..3
    const int lr   = lane & 15;       // 0..15
    const int k0   = lg * 8;
    const int s0   = blockIdx.x * 16;

    if (tid < 17) {
        const int s = s0 + tid - 1;
        smeta[tid] = (s < 0) ? 0 : endi[s];
    }
    __syncthreads();
    const int rb    = smeta[0];
    const int nrows = smeta[16] - rb;

    // ---- stage X packed, coalesced ------------------------------------------
    const int total = nrows * NRF;
    const float* __restrict__ rbase = reads + (size_t)rb * NRF;
    for (int i = tid; i < total; i += 256) {
        const int row = i / NRF;               // magic-mul
        const int col = i - row * NRF;
        XA[row][col] = to_bf(rbase[i]);
    }
    for (int r = tid; r < nrows; r += 256) {   // zero k = 11..15
        XA[r][11] = 0;
        *(short2*)&XA[r][12] = (short2){0, 0};
        *(short2*)&XA[r][14] = (short2){0, 0};
    }
    __syncthreads();

    // ---- register-resident weight fragments ---------------------------------
    bf16x8 aW0[4];                    // layer-1 A frags (W0T), k>=16 -> zero
#pragma unroll
    for (int nt = 0; nt < 4; ++nt) {
        bf16x8 z = {0, 0, 0, 0, 0, 0, 0, 0};
        if (lg < 2) z = *(const bf16x8*)&p_w0t[(nt * 16 + lr) * 16 + k0];
        aW0[nt] = z;
    }
    bf16x8 bW1[4][2];                 // layer-2 B frags
#pragma unroll
    for (int nt = 0; nt < 4; ++nt)
#pragma unroll
        for (int ks = 0; ks < 2; ++ks)
            bW1[nt][ks] = *(const bf16x8*)&p_w1t[(nt * 16 + lr) * 64 + ks * 32 + k0];
    float bias0v[4][4];               // b0[16nt + 4lg + q]
#pragma unroll
    for (int nt = 0; nt < 4; ++nt)
#pragma unroll
        for (int q = 0; q < 4; ++q) bias0v[nt][q] = b0[nt * 16 + 4 * lg + q];
    float bias1v[4];                  // b1[16nt + lr]
#pragma unroll
    for (int nt = 0; nt < 4; ++nt) bias1v[nt] = b1[nt * 16 + lr];

    // ---- main loop: 4 interleaved segments per wave -------------------------
    for (int q = 0; q < 4; ++q) {
        const int ls  = q * 4 + w;
        const int st  = smeta[ls] - rb;
        const int cnt = smeta[ls + 1] - smeta[ls];
        const int ntl = (cnt + 15) >> 4;
        float segsum[4] = {0.f, 0.f, 0.f, 0.f};

        for (int tt = 0; tt < ntl; ++tt) {
            // X fragment (B operand), row-clamped
            int lrow = st + tt * 16 + lr;
            lrow = (lrow < nrows) ? lrow : (nrows - 1);
            bf16x8 xb = {0, 0, 0, 0, 0, 0, 0, 0};
            if (lg < 2) xb = *(const bf16x8*)&XA[lrow][k0];

            // layer 1 (swapped): D_nt[q2] = H[row=lr][col=16nt+4lg+q2]
            f32x4 d[4];
#pragma unroll
            for (int nt = 0; nt < 4; ++nt) {
                f32x4 z = {0.f, 0.f, 0.f, 0.f};
                d[nt] = __builtin_amdgcn_mfma_f32_16x16x32_bf16(aW0[nt], xb, z, 0, 0, 0);
            }
            // bias + relu + packed store (4 consecutive H-cols per nt)
#pragma unroll
            for (int nt = 0; nt < 4; ++nt) {
                short4 hp;
                hp.x = to_bf(fmaxf(d[nt][0] + bias0v[nt][0], 0.f));
                hp.y = to_bf(fmaxf(d[nt][1] + bias0v[nt][1], 0.f));
                hp.z = to_bf(fmaxf(d[nt][2] + bias0v[nt][2], 0.f));
                hp.w = to_bf(fmaxf(d[nt][3] + bias0v[nt][3], 0.f));
                *(short4*)&HB[w][lr][nt * 16 + 4 * lg] = hp;
            }
            // layer 2: A = H row frags (same-wave LDS, no barrier)
            const bf16x8 h0 = *(const bf16x8*)&HB[w][lr][k0];
            const bf16x8 h1 = *(const bf16x8*)&HB[w][lr][32 + k0];
            f32x4 o[4];
#pragma unroll
            for (int nt = 0; nt < 4; ++nt) {
                f32x4 z = {0.f, 0.f, 0.f, 0.f};
                f32x4 t = __builtin_amdgcn_mfma_f32_16x16x32_bf16(h0, bW1[nt][0], z, 0, 0, 0);
                o[nt]   = __builtin_amdgcn_mfma_f32_16x16x32_bf16(h1, bW1[nt][1], t, 0, 0, 0);
            }
            // sigmoid + row mask + column sum (rows = 4lg+q2 across lanes)
            const int rowg = tt * 16 + 4 * lg;
#pragma unroll
            for (int nt = 0; nt < 4; ++nt) {
                float s = 0.f;
#pragma unroll
                for (int q2 = 0; q2 < 4; ++q2) {
                    const float p = 1.f / (1.f + __expf(-(o[nt][q2] + bias1v[nt])));
                    s += (rowg + q2 < cnt) ? p : 0.f;
                }
                s += __shfl_xor(s, 16);
                s += __shfl_xor(s, 32);
                segsum[nt] += s;
            }
        }
        if (lg == 0) {
            const float inv = 1.f / (float)cnt;
#pragma unroll
            for (int nt = 0; nt < 4; ++nt)
                means[(size_t)(s0 + ls) * 64 + nt * 16 + lr] = segsum[nt] * inv;
        }
    }
}

// ---------------------------------------------------------------------------
// K2: omega MLP on info (9 -> 64 relu -> 64 sigmoid). (unchanged)
// ---------------------------------------------------------------------------
__global__ __launch_bounds__(256) void k2_omega(
    const float* __restrict__ info,
    const float* __restrict__ w0, const float* __restrict__ b0,
    const float* __restrict__ w1, const float* __restrict__ b1,
    float* __restrict__ om)
{
    __shared__ float hbuf[4][64];
    const int lane = threadIdx.x & 63;
    const int wid  = threadIdx.x >> 6;
    const int wg   = __builtin_amdgcn_readfirstlane((int)(blockIdx.x * 4 + wid));

    float w0c[NIF];
#pragma unroll
    for (int k = 0; k < NIF; ++k) w0c[k] = w0[k * 64 + lane];
    float w1c[64];
#pragma unroll
    for (int i = 0; i < 64; ++i) w1c[i] = w1[i * 64 + lane];
    const float b0l = b0[lane];
    const float b1l = b1[lane];

    for (int i = 0; i < 8; ++i) {
        const int b = wg * 8 + i;
        const float* __restrict__ x = info + (size_t)b * NIF;
        float h = b0l;
#pragma unroll
        for (int k = 0; k < NIF; ++k) h = fmaf(x[k], w0c[k], h);
        h = fmaxf(h, 0.f);
        hbuf[wid][lane] = h;
        float o = b1l;
        const float4* h4 = (const float4*)(&hbuf[wid][0]);
#pragma unroll
        for (int q = 0; q < 16; ++q) {
            float4 hv = h4[q];
            o = fmaf(hv.x, w1c[4 * q + 0], o);
            o = fmaf(hv.y, w1c[4 * q + 1], o);
            o = fmaf(hv.z, w1c[4 * q + 2], o);
            o = fmaf(hv.w, w1c[4 * q + 3], o);
        }
        om[(size_t)b * 64 + lane] = 1.f / (1.f + __expf(-o));
    }
}

// ---------------------------------------------------------------------------
// K3: rho MLP via split-bf16 MFMA (hh + lh + hl). (unchanged from round 5)
// ---------------------------------------------------------------------------
__global__ __launch_bounds__(256) void k3_rho_mfma(
    const float* __restrict__ means, const float* __restrict__ om,
    const int* __restrict__ endi,
    const short* __restrict__ w0th, const short* __restrict__ w0tl,
    const short* __restrict__ w1th, const short* __restrict__ w1tl,
    const float* __restrict__ rb0, const float* __restrict__ rb1,
    const float* __restrict__ rw2, const float* __restrict__ rb2,
    const float* __restrict__ cw0, const float* __restrict__ cb0,
    const float* __restrict__ cw1, const float* __restrict__ cb1,
    const float* __restrict__ cw2, const float* __restrict__ cb2,
    const float* __restrict__ max_logit,
    float* __restrict__ out)
{
    __shared__ __align__(16) char smemA[18432];
    __shared__ __align__(16) char smemB[34816];
    short (*XH)[72]  = (short(*)[72])smemA;
    short (*XL)[72]  = (short(*)[72])(smemA + 9216);
    short (*HH)[136] = (short(*)[136])smemB;
    short (*HL)[136] = (short(*)[136])(smemB + 17408);
    float (*h2T)[68] = (float(*)[68])smemA;

    const int tid  = threadIdx.x;
    const int lane = tid & 63;
    const int w    = tid >> 6;
    const int lg   = lane >> 4;
    const int lr   = lane & 15;
    const int k0   = lg * 8;
    const int b0i  = blockIdx.x * 64;

    const int wbase = w * 32;
    float bias0[2];
#pragma unroll
    for (int nt = 0; nt < 2; ++nt) bias0[nt] = rb0[wbase + nt * 16 + lr];

    f32x4 acc[4][2];
#pragma unroll
    for (int rt = 0; rt < 4; ++rt)
#pragma unroll
        for (int nt = 0; nt < 2; ++nt) acc[rt][nt] = (f32x4){0.f, 0.f, 0.f, 0.f};

    for (int c = 0; c < 3; ++c) {
        const float* __restrict__ src =
            (c == 0) ? means + (size_t)b0i * 64 :
            (c == 1) ? means + (size_t)(NB + b0i) * 64 :
                       om    + (size_t)b0i * 64;
        __syncthreads();
        for (int idx = tid; idx < 64 * 64; idx += 256) {
            const int row = idx >> 6, col = idx & 63;
            const float v = src[(size_t)row * 64 + col];
            const short hi = to_bf(v);
            const short lo = to_bf(v - bf2f(hi));
            XH[row][col] = hi;
            XL[row][col] = lo;
        }
        __syncthreads();

#pragma unroll
        for (int ks = 0; ks < 2; ++ks) {
            const int koff = c * 64 + ks * 32 + k0;
            bf16x8 Bh[2], Bl[2];
#pragma unroll
            for (int nt = 0; nt < 2; ++nt) {
                const int col = wbase + nt * 16 + lr;
                Bh[nt] = *(const bf16x8*)&w0th[(size_t)col * 192 + koff];
                Bl[nt] = *(const bf16x8*)&w0tl[(size_t)col * 192 + koff];
            }
#pragma unroll
            for (int rt = 0; rt < 4; ++rt) {
                const bf16x8 Ah = *(const bf16x8*)&XH[rt * 16 + lr][ks * 32 + k0];
                const bf16x8 Al = *(const bf16x8*)&XL[rt * 16 + lr][ks * 32 + k0];
#pragma unroll
                for (int nt = 0; nt < 2; ++nt) {
                    acc[rt][nt] = __builtin_amdgcn_mfma_f32_16x16x32_bf16(Ah, Bh[nt], acc[rt][nt], 0, 0, 0);
                    acc[rt][nt] = __builtin_amdgcn_mfma_f32_16x16x32_bf16(Al, Bh[nt], acc[rt][nt], 0, 0, 0);
                    acc[rt][nt] = __builtin_amdgcn_mfma_f32_16x16x32_bf16(Ah, Bl[nt], acc[rt][nt], 0, 0, 0);
                }
            }
        }
    }
    __syncthreads();
#pragma unroll
    for (int rt = 0; rt < 4; ++rt)
#pragma unroll
        for (int nt = 0; nt < 2; ++nt)
#pragma unroll
            for (int r = 0; r < 4; ++r) {
                const int row = rt * 16 + 4 * lg + r;
                const int col = wbase + nt * 16 + lr;
                const float v = fmaxf(acc[rt][nt][r] + bias0[nt], 0.f);
                const short hi = to_bf(v);
                HH[row][col] = hi;
                HL[row][col] = to_bf(v - bf2f(hi));
            }
    __syncthreads();

    const int cbase = w * 16;
    const float bias1 = rb1[cbase + lr];
    f32x4 acc2[4];
#pragma unroll
    for (int rt = 0; rt < 4; ++rt) acc2[rt] = (f32x4){0.f, 0.f, 0.f, 0.f};

#pragma unroll
    for (int ks = 0; ks < 4; ++ks) {
        const int koff = ks * 32 + k0;
        const int col  = cbase + lr;
        const bf16x8 Bh = *(const bf16x8*)&w1th[(size_t)col * 128 + koff];
        const bf16x8 Bl = *(const bf16x8*)&w1tl[(size_t)col * 128 + koff];
#pragma unroll
        for (int rt = 0; rt < 4; ++rt) {
            const bf16x8 Ah = *(const bf16x8*)&HH[rt * 16 + lr][koff];
            const bf16x8 Al = *(const bf16x8*)&HL[rt * 16 + lr][koff];
            acc2[rt] = __builtin_amdgcn_mfma_f32_16x16x32_bf16(Ah, Bh, acc2[rt], 0, 0, 0);
            acc2[rt] = __builtin_amdgcn_mfma_f32_16x16x32_bf16(Al, Bh, acc2[rt], 0, 0, 0);
            acc2[rt] = __builtin_amdgcn_mfma_f32_16x16x32_bf16(Ah, Bl, acc2[rt], 0, 0, 0);
        }
    }
#pragma unroll
    for (int rt = 0; rt < 4; ++rt)
#pragma unroll
        for (int r = 0; r < 4; ++r)
            h2T[cbase + lr][rt * 16 + 4 * lg + r] = fmaxf(acc2[rt][r] + bias1, 0.f);
    __syncthreads();

    if (w == 0) {
        const int b = b0i + lane;
        float l0 = rb2[0], l1 = 0.f, l2 = 0.f, l3 = 0.f;
#pragma unroll
        for (int j = 0; j < 16; ++j) {
            l0 = fmaf(h2T[j][lane],      rw2[j],      l0);
            l1 = fmaf(h2T[16 + j][lane], rw2[16 + j], l1);
            l2 = fmaf(h2T[32 + j][lane], rw2[32 + j], l2);
            l3 = fmaf(h2T[48 + j][lane], rw2[48 + j], l3);
        }
        const float logit = (l0 + l1) + (l2 + l3);

        const int er1 = endi[b];
        const int er0 = (b == 0) ? 0 : endi[b - 1];
        const int ea1 = endi[NB + b];
        const int ea0 = endi[NB + b - 1];
        const float x0 = sqrtf((float)(ea1 - ea0));
        const float x1 = sqrtf((float)(er1 - er0));

        float t5[5];
#pragma unroll
        for (int m = 0; m < 5; ++m)
            t5[m] = fmaxf(cb0[m] + x0 * cw0[m] + x1 * cw0[5 + m], 0.f);
        float t5b[5];
#pragma unroll
        for (int m = 0; m < 5; ++m) {
            float v = cb1[m];
#pragma unroll
            for (int i = 0; i < 5; ++i) v = fmaf(t5[i], cw1[i * 5 + m], v);
            t5b[m] = fmaxf(v, 0.f);
        }
        float temp = cb2[0];
#pragma unroll
        for (int m = 0; m < 5; ++m) temp = fmaf(t5b[m], cw2[m], temp);

        const float ml = max_logit[0];
        out[b] = ml * tanhf((logit * temp) / ml);
    }
}

// ---------------------------------------------------------------------------
extern "C" void kernel_launch(void* const* d_in, const int* in_sizes, int n_in,
                              void* d_out, int out_size, void* d_ws, size_t ws_size,
                              hipStream_t stream)
{
    const float* reads  = (const float*)d_in[0];
    const float* info   = (const float*)d_in[1];
    const int*   endi   = (const int*)d_in[2];       // int64 inputs arrive as int32
    const float* phi_w0 = (const float*)d_in[3];
    const float* phi_b0 = (const float*)d_in[4];
    const float* phi_w1 = (const float*)d_in[5];
    const float* phi_b1 = (const float*)d_in[6];
    const float* om_w0  = (const float*)d_in[7];
    const float* om_b0  = (const float*)d_in[8];
    const float* om_w1  = (const float*)d_in[9];
    const float* om_b1  = (const float*)d_in[10];
    const float* rw0    = (const float*)d_in[11];
    const float* rb0    = (const float*)d_in[12];
    const float* rw1    = (const float*)d_in[13];
    const float* rb1    = (const float*)d_in[14];
    const float* rw2    = (const float*)d_in[15];
    const float* rb2    = (const float*)d_in[16];
    const float* cw0    = (const float*)d_in[17];
    const float* cb0    = (const float*)d_in[18];
    const float* cw1    = (const float*)d_in[19];
    const float* cb1    = (const float*)d_in[20];
    const float* cw2    = (const float*)d_in[21];
    const float* cb2    = (const float*)d_in[22];
    const float* mlog   = (const float*)d_in[23];

    char* ws = (char*)d_ws;
    float* means = (float*)ws;                                   // 16,777,216 B
    float* om    = (float*)(ws + 16777216);                      //  8,388,608 B
    short* w0th  = (short*)(ws + 25165824);                      //     49,152 B
    short* w0tl  = (short*)(ws + 25165824 + 49152);              //     49,152 B
    short* w1th  = (short*)(ws + 25165824 + 98304);              //     16,384 B
    short* w1tl  = (short*)(ws + 25165824 + 114688);             //     16,384 B
    short* p_w0t = (short*)(ws + 25165824 + 131072);             //      2,048 B
    short* p_w1t = (short*)(ws + 25165824 + 133120);             //      8,192 B
    float* out   = (float*)d_out;

    // K0: one-time weight prep (rho split planes + phi bf16 transposes)
    hipLaunchKernelGGL(k0_prep, dim3(96), dim3(256), 0, stream,
                       rw0, rw1, phi_w0, phi_w1,
                       w0th, w0tl, w1th, w1tl, p_w0t, p_w1t);
    // K1: 16 segments per block -> 4096 blocks
    hipLaunchKernelGGL(k1_phi_mfma2, dim3(4096), dim3(256), 0, stream,
                       reads, endi, p_w0t, p_w1t, phi_b0, phi_b1, means);
    // K2: 32768 rows, 8 per wave, 4 waves/block -> 1024 blocks
    hipLaunchKernelGGL(k2_omega, dim3(1024), dim3(256), 0, stream,
                       info, om_w0, om_b0, om_w1, om_b1, om);
    // K3: 64 rows per block -> 512 blocks x 256 threads
    hipLaunchKernelGGL(k3_rho_mfma, dim3(512), dim3(256), 0, stream,
                       means, om, endi, w0th, w0tl, w1th, w1tl,
                       rb0, rb1, rw2, rb2,
                       cw0, cb0, cw1, cb1, cw2, cb2, mlog, out);
}